// Round 1
// 362.304 us; speedup vs baseline: 1.0314x; 1.0314x over previous
//
#include <hip/hip_runtime.h>

#define NGRAPH 64
#define DIMT   240
#define DIMT4  60
#define EPS    1e-5f
#define ROWS   100   // rows per block; 200000/100 = 2000 blocks (7.8/CU, small tail)

typedef float f32x4 __attribute__((ext_vector_type(4)));

// ---------------------------------------------------------------------------
// Kernel 1: per-graph statistics, coalesced + 4x unrolled (4 loads in flight).
// tid -> (r_off = tid/60, j = tid%60); note (rbase+r_off)*60 + j == rbase*60+tid,
// so all 240 active threads read one contiguous 3840B burst per 4-row group.
// Main loop processes 16 rows/iter with 4 independent dwordx4 loads per wave
// (MLP=4); remainder loop handles <16 leftover rows. batch is SORTED ->
// per-segment register accumulate, LDS-reduce, 12 global atomics per flush.
// gstats per graph (12 floats): [0]=count, [1]=sum(l0), [2]=sumsq(l0),
// [3..5]=sum(l1 per d), [6..10]=sum(l2 per d).
// ---------------------------------------------------------------------------
__global__ __launch_bounds__(256) void stats_kernel(const float* __restrict__ x,
                                                    const int* __restrict__ batch,
                                                    float* __restrict__ gstats, int n)
{
    __shared__ int    sbatch[ROWS];
    __shared__ float4 ssum[240];
    __shared__ float4 ssq[64];
    __shared__ float  lstat[12];

    const int tid = threadIdx.x;
    const int r0 = blockIdx.x * ROWS;
    const int r1 = min(n, r0 + ROWS);
    if (r0 >= n) return;
    for (int i = tid; i < r1 - r0; i += 256) sbatch[i] = batch[r0 + i];
    __syncthreads();

    const bool active = tid < 240;
    const int  r_off  = tid / 60;
    const int  j      = tid - r_off * 60;           // float4 column in [0,60)
    const float4* x4  = (const float4*)x;

    int r = r0;
    while (r < r1) {
        const int b_cur = sbatch[r - r0];
        // binary search for first row in (r, r1) with batch > b_cur (sorted)
        int lo = r + 1, hi = r1;
        while (lo < hi) {
            int mid = (lo + hi) >> 1;
            if (sbatch[mid - r0] <= b_cur) lo = mid + 1; else hi = mid;
        }
        const int r_end = lo;

        float4 sum = {0.f, 0.f, 0.f, 0.f};
        float4 sq  = {0.f, 0.f, 0.f, 0.f};
        if (active) {
            const bool dosq = (j < 16);
            int rbase = r;
            // main loop: 16 rows per iteration, 4 independent loads in flight
            for (; rbase + 16 <= r_end; rbase += 16) {
                size_t i0 = (size_t)rbase * DIMT4 + tid;
                float4 v0 = x4[i0];
                float4 v1 = x4[i0 + 240];
                float4 v2 = x4[i0 + 480];
                float4 v3 = x4[i0 + 720];
                sum.x += (v0.x + v1.x) + (v2.x + v3.x);
                sum.y += (v0.y + v1.y) + (v2.y + v3.y);
                sum.z += (v0.z + v1.z) + (v2.z + v3.z);
                sum.w += (v0.w + v1.w) + (v2.w + v3.w);
                if (dosq) {
                    sq.x = fmaf(v0.x, v0.x, fmaf(v1.x, v1.x, fmaf(v2.x, v2.x, fmaf(v3.x, v3.x, sq.x))));
                    sq.y = fmaf(v0.y, v0.y, fmaf(v1.y, v1.y, fmaf(v2.y, v2.y, fmaf(v3.y, v3.y, sq.y))));
                    sq.z = fmaf(v0.z, v0.z, fmaf(v1.z, v1.z, fmaf(v2.z, v2.z, fmaf(v3.z, v3.z, sq.z))));
                    sq.w = fmaf(v0.w, v0.w, fmaf(v1.w, v1.w, fmaf(v2.w, v2.w, fmaf(v3.w, v3.w, sq.w))));
                }
            }
            // remainder (< 16 rows)
            for (; rbase < r_end; rbase += 4) {
                int rr = rbase + r_off;
                if (rr < r_end) {
                    float4 v = x4[(size_t)rr * DIMT4 + j];
                    sum.x += v.x; sum.y += v.y; sum.z += v.z; sum.w += v.w;
                    if (dosq) {
                        sq.x = fmaf(v.x, v.x, sq.x); sq.y = fmaf(v.y, v.y, sq.y);
                        sq.z = fmaf(v.z, v.z, sq.z); sq.w = fmaf(v.w, v.w, sq.w);
                    }
                }
            }
        }
        // ---- block flush ----
        if (active) ssum[tid] = sum;
        if (active && j < 16) ssq[r_off * 16 + j] = sq;
        if (tid < 12) lstat[tid] = 0.f;
        __syncthreads();
        if (tid < 60) {
            float4 t0 = ssum[tid], t1 = ssum[60 + tid], t2 = ssum[120 + tid], t3 = ssum[180 + tid];
            float4 s4;
            s4.x = t0.x + t1.x + t2.x + t3.x;
            s4.y = t0.y + t1.y + t2.y + t3.y;
            s4.z = t0.z + t1.z + t2.z + t3.z;
            s4.w = t0.w + t1.w + t2.w + t3.w;
            if (tid < 16) {                          // l=0 columns 0..63
                atomicAdd(&lstat[0], s4.x + s4.y + s4.z + s4.w);
                float4 q0 = ssq[tid], q1 = ssq[16 + tid], q2 = ssq[32 + tid], q3 = ssq[48 + tid];
                float qs = (q0.x + q0.y + q0.z + q0.w) + (q1.x + q1.y + q1.z + q1.w)
                         + (q2.x + q2.y + q2.z + q2.w) + (q3.x + q3.y + q3.z + q3.w);
                atomicAdd(&lstat[1], qs);
            } else if (tid < 40) {                   // l=1, col = 4*tid+comp, d=(col-64)%3
                int base = 4 * tid - 64;
                atomicAdd(&lstat[2 + (base + 0) % 3], s4.x);
                atomicAdd(&lstat[2 + (base + 1) % 3], s4.y);
                atomicAdd(&lstat[2 + (base + 2) % 3], s4.z);
                atomicAdd(&lstat[2 + (base + 3) % 3], s4.w);
            } else {                                 // l=2, d=(col-160)%5
                int base = 4 * tid - 160;
                atomicAdd(&lstat[5 + (base + 0) % 5], s4.x);
                atomicAdd(&lstat[5 + (base + 1) % 5], s4.y);
                atomicAdd(&lstat[5 + (base + 2) % 5], s4.z);
                atomicAdd(&lstat[5 + (base + 3) % 5], s4.w);
            }
        }
        __syncthreads();
        if (tid < 11) atomicAdd(gstats + b_cur * 12 + 1 + tid, lstat[tid]);
        if (tid == 0) atomicAdd(gstats + b_cur * 12 + 0, (float)(r_end - r));
        __syncthreads();                             // protect lstat/ssum reuse
        r = r_end;
    }
}

// ---------------------------------------------------------------------------
// Kernel 2: finalize stats into per-(graph,col) affine table: y = x*A + B.
// ---------------------------------------------------------------------------
__global__ __launch_bounds__(256) void finalize_kernel(const float* __restrict__ gstats,
                                                       const float* __restrict__ weight,
                                                       const float* __restrict__ bias,
                                                       float* __restrict__ A,
                                                       float* __restrict__ B)
{
    int b = blockIdx.x;
    int c = threadIdx.x;
    if (c >= DIMT) return;
    const float* st = gstats + b * 12;
    float cnt   = fmaxf(st[0], 1.f);
    float mean0 = st[1] / (cnt * 64.f);
    float ex2   = st[2] / (cnt * 64.f);
    float norm  = fmaxf(ex2 - mean0 * mean0, 0.f);
    float scale = 1.f / (sqrtf(norm) + EPS);
    float a, bb;
    if (c < 64) {                       // l=0: normalize + weight + bias
        float w = weight[c];
        a  = scale * w;
        bb = bias[c] - mean0 * a;
    } else if (c < 160) {               // l=1: mean-subtract + weight
        int jj = c - 64;
        int d = jj % 3, m = jj / 3;
        float w = weight[64 + m];
        float mean = st[3 + d] / (cnt * 32.f);
        a = w; bb = -mean * w;
    } else {                            // l=2
        int jj = c - 160;
        int d = jj % 5, m = jj / 5;
        float w = weight[96 + m];
        float mean = st[6 + d] / (cnt * 16.f);
        a = w; bb = -mean * w;
    }
    A[b * DIMT + c] = a;
    B[b * DIMT + c] = bb;
}

// ---------------------------------------------------------------------------
// Kernel 3: apply, coalesced + register-cached A/B + 4x unroll + NT stores.
// Per graph segment: load A/B float4 for (b_cur, j) ONCE into registers, then
// stream 16 rows/iter with 4 loads in flight. Stores are non-temporal so the
// 192 MB output doesn't evict x from the 256 MB L3 (x was just brought in by
// stats_kernel; apply's reads should stay L3 hits).
// ---------------------------------------------------------------------------
__global__ __launch_bounds__(256) void apply_kernel(const float* __restrict__ x,
                                                    const int* __restrict__ batch,
                                                    const float* __restrict__ A,
                                                    const float* __restrict__ B,
                                                    float* __restrict__ out, int n)
{
    __shared__ int sbatch[ROWS];
    const int tid = threadIdx.x;
    const int r0 = blockIdx.x * ROWS;
    const int r1 = min(n, r0 + ROWS);
    if (r0 >= n) return;
    for (int i = tid; i < r1 - r0; i += 256) sbatch[i] = batch[r0 + i];
    __syncthreads();

    const bool active = tid < 240;
    const int  r_off  = tid / 60;
    const int  j      = tid - r_off * 60;
    const f32x4* x4   = (const f32x4*)x;
    f32x4*       o4   = (f32x4*)out;

    int r = r0;
    while (r < r1) {
        const int b_cur = sbatch[r - r0];
        int lo = r + 1, hi = r1;
        while (lo < hi) {
            int mid = (lo + hi) >> 1;
            if (sbatch[mid - r0] <= b_cur) lo = mid + 1; else hi = mid;
        }
        const int r_end = lo;

        if (active) {
            const f32x4 a  = ((const f32x4*)(A + b_cur * DIMT))[j];
            const f32x4 bb = ((const f32x4*)(B + b_cur * DIMT))[j];
            int rbase = r;
            for (; rbase + 16 <= r_end; rbase += 16) {
                size_t i0 = (size_t)rbase * DIMT4 + tid;
                f32x4 v0 = x4[i0];
                f32x4 v1 = x4[i0 + 240];
                f32x4 v2 = x4[i0 + 480];
                f32x4 v3 = x4[i0 + 720];
                f32x4 o0, o1, o2, o3;
                o0.x = fmaf(v0.x, a.x, bb.x); o0.y = fmaf(v0.y, a.y, bb.y);
                o0.z = fmaf(v0.z, a.z, bb.z); o0.w = fmaf(v0.w, a.w, bb.w);
                o1.x = fmaf(v1.x, a.x, bb.x); o1.y = fmaf(v1.y, a.y, bb.y);
                o1.z = fmaf(v1.z, a.z, bb.z); o1.w = fmaf(v1.w, a.w, bb.w);
                o2.x = fmaf(v2.x, a.x, bb.x); o2.y = fmaf(v2.y, a.y, bb.y);
                o2.z = fmaf(v2.z, a.z, bb.z); o2.w = fmaf(v2.w, a.w, bb.w);
                o3.x = fmaf(v3.x, a.x, bb.x); o3.y = fmaf(v3.y, a.y, bb.y);
                o3.z = fmaf(v3.z, a.z, bb.z); o3.w = fmaf(v3.w, a.w, bb.w);
                __builtin_nontemporal_store(o0, &o4[i0]);
                __builtin_nontemporal_store(o1, &o4[i0 + 240]);
                __builtin_nontemporal_store(o2, &o4[i0 + 480]);
                __builtin_nontemporal_store(o3, &o4[i0 + 720]);
            }
            for (; rbase < r_end; rbase += 4) {
                int rr = rbase + r_off;
                if (rr < r_end) {
                    size_t idx = (size_t)rr * DIMT4 + j;
                    f32x4 v = x4[idx];
                    f32x4 o;
                    o.x = fmaf(v.x, a.x, bb.x);
                    o.y = fmaf(v.y, a.y, bb.y);
                    o.z = fmaf(v.z, a.z, bb.z);
                    o.w = fmaf(v.w, a.w, bb.w);
                    __builtin_nontemporal_store(o, &o4[idx]);
                }
            }
        }
        r = r_end;
    }
}

extern "C" void kernel_launch(void* const* d_in, const int* in_sizes, int n_in,
                              void* d_out, int out_size, void* d_ws, size_t ws_size,
                              hipStream_t stream) {
    const float* x      = (const float*)d_in[0];
    const int*   batch  = (const int*)d_in[1];
    const float* weight = (const float*)d_in[2];
    const float* bias   = (const float*)d_in[3];
    float*       out    = (float*)d_out;
    int n = in_sizes[1];                        // 200000 nodes

    float* gstats = (float*)d_ws;                                   // 64*12 floats
    float* A = (float*)((char*)d_ws + 4096);                        // 64*240 floats
    float* B = (float*)((char*)d_ws + 4096 + NGRAPH * DIMT * 4);    // 64*240 floats

    hipMemsetAsync(d_ws, 0, NGRAPH * 12 * sizeof(float), stream);

    int nblocks = (n + ROWS - 1) / ROWS;
    stats_kernel<<<nblocks, 256, 0, stream>>>(x, batch, gstats, n);
    finalize_kernel<<<NGRAPH, 256, 0, stream>>>(gstats, weight, bias, A, B);
    apply_kernel<<<nblocks, 256, 0, stream>>>(x, batch, A, B, out, n);
}